// Round 2
// baseline (471.804 us; speedup 1.0000x reference)
//
#include <hip/hip_runtime.h>
#include <hip/hip_bf16.h>
#include <stdint.h>

#define NROWS 8192
#define DDIM  256
#define SIGMA_INV 10.0f

#define BM 64
#define BN 64
#define NSPLIT 8
#define JCHUNK (NROWS / NSPLIT)   // 1024
#define NITER  (JCHUNK / BN)      // 16
#define PSTR   72                 // P LDS row stride in halfs: 144B = 36 words -> +4 banks/row, 2-way max

typedef __attribute__((ext_vector_type(8))) short bf16x8;   // 8 bf16 = 4 VGPRs
typedef __attribute__((ext_vector_type(4))) float f32x4;

__device__ inline unsigned short f2bf(float x) {
  __hip_bfloat16 h = __float2bfloat16(x);
  return *reinterpret_cast<unsigned short*>(&h);
}

// ---------------- K0: L2-normalize rows -> bf16 ----------------
__global__ __launch_bounds__(256) void normalize_k(const float* __restrict__ emb,
                                                   unsigned short* __restrict__ embn) {
  const int w = threadIdx.x >> 6, lane = threadIdx.x & 63;
  const int row = blockIdx.x * 4 + w;
  const float4* src = (const float4*)(emb + (size_t)row * DDIM);
  float4 v = src[lane];
  float ss = v.x * v.x + v.y * v.y + v.z * v.z + v.w * v.w;
  for (int off = 32; off >= 1; off >>= 1) ss += __shfl_xor(ss, off);
  const float sc = 1.0f / fmaxf(sqrtf(ss), 1e-12f);
  ushort4 o;
  o.x = f2bf(v.x * sc); o.y = f2bf(v.y * sc);
  o.z = f2bf(v.z * sc); o.w = f2bf(v.w * sc);
  ((ushort4*)(embn + (size_t)row * DDIM))[lane] = o;
}

// ---------------- K0b: emb[N][D] fp32 -> vt[D][N] bf16 ----------------
__global__ __launch_bounds__(256) void transpose_k(const float* __restrict__ emb,
                                                   unsigned short* __restrict__ vt) {
  __shared__ float tile[64][65];
  const int r0 = blockIdx.x * 64, c0 = blockIdx.y * 64;
  const int tr = threadIdx.x >> 6, tc = threadIdx.x & 63;
  for (int i = 0; i < 16; ++i)
    tile[i * 4 + tr][tc] = emb[(size_t)(r0 + i * 4 + tr) * DDIM + c0 + tc];
  __syncthreads();
  for (int i = 0; i < 16; ++i)
    vt[(size_t)(c0 + i * 4 + tr) * NROWS + r0 + tc] = f2bf(tile[tc][i * 4 + tr]);
}

// ---------------- F: fused  S=Qn.Knt -> exp -> O += P.V, row sums ----------------
// grid = 128 mblk x 8 chunks = 1024 blocks, 256 threads (4 waves = 2 m-groups x 2 d-halves)
// No K LDS tile: G1 B-frags read straight from global embn (L2-resident; 4 q-lanes
// consume one full 64B line per row -> no wasted fetch, no 16-way LDS bank conflict,
// no DMA-drain barrier). Only pl (P transit) lives in LDS, double-buffered ->
// ONE barrier per K-iteration.
__global__ __launch_bounds__(256, 4) void fused_k(
    const unsigned short* __restrict__ embn,  // [N][D] bf16
    const unsigned short* __restrict__ vt,    // [D][N] bf16
    float* __restrict__ out,                  // [N][D] fp32, pre-zeroed, atomic accum
    float* __restrict__ l_part)               // [N] fp32, pre-zeroed, atomic accum
{
  __shared__ unsigned short pl[2][BM * PSTR]; // 2 x 9 KB

  const int tid = threadIdx.x;
  const int w = tid >> 6, lane = tid & 63;
  const int mg = w >> 1, dh = w & 1;          // m-group, d-half
  const int q = lane >> 4, c = lane & 15;
  const int chunk = blockIdx.x & 7;           // == XCD id under round-robin: each XCD's
  const int mblk = blockIdx.x >> 3;           //    L2 serves one 1MB j-slice of embn/vt
  const int row0 = mblk * BM + mg * 32;
  const size_t j0base = (size_t)chunk * JCHUNK;

  // Q fragments resident in registers: A[m=lane&15][k=q*8+j]
  bf16x8 qa[2][8];
  for (int mt = 0; mt < 2; ++mt)
    for (int k = 0; k < 8; ++k)
      qa[mt][k] = *(const bf16x8*)(embn + (size_t)(row0 + mt * 16 + c) * DDIM + k * 32 + q * 8);

  f32x4 oacc[2][8];
  for (int mt = 0; mt < 2; ++mt)
    for (int u = 0; u < 8; ++u) oacc[mt][u] = {0.f, 0.f, 0.f, 0.f};
  float lacc[2][4] = {};

  for (int it = 0; it < NITER; ++it) {
    const size_t j0 = j0base + (size_t)it * BN;
    const int buf = it & 1;

    // ---- G1: S[32x64] = Q . Kn^T, B-frags direct from global ----
    f32x4 sacc[2][2];
    for (int mt = 0; mt < 2; ++mt)
      for (int nt = 0; nt < 2; ++nt) sacc[mt][nt] = {0.f, 0.f, 0.f, 0.f};
    const unsigned short* kb = embn + j0 * DDIM;
    for (int k = 0; k < 8; ++k) {
      bf16x8 b0 = *(const bf16x8*)(kb + (size_t)(dh * 32 + c) * DDIM + k * 32 + q * 8);
      bf16x8 b1 = *(const bf16x8*)(kb + (size_t)(dh * 32 + 16 + c) * DDIM + k * 32 + q * 8);
      for (int mt = 0; mt < 2; ++mt) {
        sacc[mt][0] = __builtin_amdgcn_mfma_f32_16x16x32_bf16(qa[mt][k], b0, sacc[mt][0], 0, 0, 0);
        sacc[mt][1] = __builtin_amdgcn_mfma_f32_16x16x32_bf16(qa[mt][k], b1, sacc[mt][1], 0, 0, 0);
      }
    }

    // exp (fixed shift 10 = global logit max; softmax shift-invariant) + P write + row-sum partials
    for (int mt = 0; mt < 2; ++mt)
      for (int nt = 0; nt < 2; ++nt)
        for (int r = 0; r < 4; ++r) {
          const float p = __expf(fmaf(SIGMA_INV, sacc[mt][nt][r], -SIGMA_INV));
          lacc[mt][r] += p;
          // C/D layout: row = q*4+r, col = c
          pl[buf][(mg * 32 + mt * 16 + q * 4 + r) * PSTR + dh * 32 + nt * 16 + c] = f2bf(p);
        }

    __syncthreads();  // P[buf] complete. (Overwrite of pl[buf] next-next iter is fenced
                      // by the barrier of iter it+1, whose waitcnt drains this iter's reads.)

    // ---- G2: O[32x128] += P[32x64] . V[64x128] (B from global vt, L2-resident) ----
    for (int kk = 0; kk < 2; ++kk) {
      bf16x8 ap0 = *(const bf16x8*)(pl[buf] + (mg * 32 + c) * PSTR + kk * 32 + q * 8);
      bf16x8 ap1 = *(const bf16x8*)(pl[buf] + (mg * 32 + 16 + c) * PSTR + kk * 32 + q * 8);
      for (int u = 0; u < 8; ++u) {
        const int d = dh * 128 + u * 16 + c;
        bf16x8 bv = *(const bf16x8*)(vt + (size_t)d * NROWS + j0 + kk * 32 + q * 8);
        oacc[0][u] = __builtin_amdgcn_mfma_f32_16x16x32_bf16(ap0, bv, oacc[0][u], 0, 0, 0);
        oacc[1][u] = __builtin_amdgcn_mfma_f32_16x16x32_bf16(ap1, bv, oacc[1][u], 0, 0, 0);
      }
    }
  }

  // epilogue: row-sum reduce across the 16 c-lanes (same q), then device atomics
  for (int mt = 0; mt < 2; ++mt)
    for (int r = 0; r < 4; ++r) {
      float s = lacc[mt][r];
      s += __shfl_xor(s, 1); s += __shfl_xor(s, 2);
      s += __shfl_xor(s, 4); s += __shfl_xor(s, 8);
      if (c == 0)
        atomicAdd(&l_part[row0 + mt * 16 + q * 4 + r], s);
    }
  for (int mt = 0; mt < 2; ++mt)
    for (int u = 0; u < 8; ++u)
      for (int r = 0; r < 4; ++r)
        atomicAdd(&out[(size_t)(row0 + mt * 16 + q * 4 + r) * DDIM + dh * 128 + u * 16 + c],
                  oacc[mt][u][r]);
}

// ---------------- K4: divide by row sums ----------------
__global__ __launch_bounds__(256) void finalize_k(float* __restrict__ out,
                                                  const float* __restrict__ l_part) {
  const int row = blockIdx.x, t = threadIdx.x;
  out[(size_t)row * DDIM + t] /= l_part[row];
}

extern "C" void kernel_launch(void* const* d_in, const int* in_sizes, int n_in,
                              void* d_out, int out_size, void* d_ws, size_t ws_size,
                              hipStream_t stream) {
  const float* emb = (const float*)d_in[0];
  float* out = (float*)d_out;
  char* ws = (char*)d_ws;
  // ws layout: embn 4MB | vt 4MB | l_part 32KB   (total ~8.03 MB, <= round-1 footprint)
  unsigned short* embn = (unsigned short*)ws;
  unsigned short* vt   = (unsigned short*)(ws + ((size_t)4 << 20));
  float* l_part        = (float*)(ws + ((size_t)8 << 20));

  hipMemsetAsync(out, 0, (size_t)NROWS * DDIM * sizeof(float), stream);
  hipMemsetAsync(l_part, 0, (size_t)NROWS * sizeof(float), stream);

  normalize_k<<<NROWS / 4, 256, 0, stream>>>(emb, embn);
  transpose_k<<<dim3(NROWS / 64, DDIM / 64), 256, 0, stream>>>(emb, vt);
  fused_k<<<(NROWS / BM) * NSPLIT, 256, 0, stream>>>(embn, vt, out, l_part);
  finalize_k<<<NROWS, 256, 0, stream>>>(out, l_part);
}

// Round 3
// 237.383 us; speedup vs baseline: 1.9875x; 1.9875x over previous
//
#include <hip/hip_runtime.h>
#include <hip/hip_bf16.h>
#include <stdint.h>

#define NROWS 8192
#define DDIM  256
#define SIGMA_INV 10.0f

#define BM 64
#define BN 64
#define NSPLIT 4
#define JCHUNK (NROWS / NSPLIT)   // 2048
#define NITER  (JCHUNK / BN)      // 32
#define PSTR   72                 // pl row stride in halfs (144B, 16B-aligned)
#define KCHB   1056               // DMA chunk pitch: 1024B payload + 32B pad -> conflict-free reads

typedef __attribute__((ext_vector_type(8))) short bf16x8;
typedef __attribute__((ext_vector_type(4))) float f32x4;

__device__ inline unsigned short f2bf(float x) {
  __hip_bfloat16 h = __float2bfloat16(x);
  return *reinterpret_cast<unsigned short*>(&h);
}

__device__ inline void dma16(const void* g, void* l) {
  __builtin_amdgcn_global_load_lds(
      (const __attribute__((address_space(1))) unsigned int*)g,
      (__attribute__((address_space(3))) unsigned int*)l, 16, 0, 0);
}

// ---------------- K0: L2-normalize rows -> bf16 ----------------
__global__ __launch_bounds__(256) void normalize_k(const float* __restrict__ emb,
                                                   unsigned short* __restrict__ embn) {
  const int w = threadIdx.x >> 6, lane = threadIdx.x & 63;
  const int row = blockIdx.x * 4 + w;
  const float4* src = (const float4*)(emb + (size_t)row * DDIM);
  float4 v = src[lane];
  float ss = v.x * v.x + v.y * v.y + v.z * v.z + v.w * v.w;
  for (int off = 32; off >= 1; off >>= 1) ss += __shfl_xor(ss, off);
  const float sc = 1.0f / fmaxf(sqrtf(ss), 1e-12f);
  ushort4 o;
  o.x = f2bf(v.x * sc); o.y = f2bf(v.y * sc);
  o.z = f2bf(v.z * sc); o.w = f2bf(v.w * sc);
  ((ushort4*)(embn + (size_t)row * DDIM))[lane] = o;
}

// ---------------- K0b: emb[N][D] fp32 -> vt[D][N] bf16 ----------------
__global__ __launch_bounds__(256) void transpose_k(const float* __restrict__ emb,
                                                   unsigned short* __restrict__ vt) {
  __shared__ float tile[64][65];
  const int r0 = blockIdx.x * 64, c0 = blockIdx.y * 64;
  const int tr = threadIdx.x >> 6, tc = threadIdx.x & 63;
  for (int i = 0; i < 16; ++i)
    tile[i * 4 + tr][tc] = emb[(size_t)(r0 + i * 4 + tr) * DDIM + c0 + tc];
  __syncthreads();
  for (int i = 0; i < 16; ++i)
    vt[(size_t)(c0 + i * 4 + tr) * NROWS + r0 + tc] = f2bf(tile[tc][i * 4 + tr]);
}

// ---------------- F: fused  S=Qn.Knt -> exp -> O += P.V, row sums ----------------
// grid = 128 mblk x 4 chunks = 512 blocks (exactly 2/CU), 256 threads
// kn staged by global_load_lds into PADDED chunks (pitch 1056B): B-frag ds_read_b128
// lands 8 lanes per 4-bank span = conflict-free floor. vt frags prefetched into
// registers before B2 (pre-barrier vmcnt(0) completes them "for free").
// chunk = blockIdx&3: under %8 XCD round-robin each XCD serves ONE 2MB j-slice.
__global__ __launch_bounds__(256, 2) void fused_k(
    const unsigned short* __restrict__ embn,  // [N][D] bf16
    const unsigned short* __restrict__ vt,    // [D][N] bf16
    float* __restrict__ out,                  // [N][D] fp32, pre-zeroed, atomic accum
    float* __restrict__ l_part)               // [N] fp32, pre-zeroed, atomic accum
{
  __shared__ char kn[32 * KCHB];              // 33 KB, padded DMA-staged K-tile
  __shared__ unsigned short pl[BM * PSTR];    // 9 KB, P transit (single buffer: 2 barriers/iter)

  const int tid = threadIdx.x;
  const int w = tid >> 6, lane = tid & 63;
  const int mg = w >> 1, dh = w & 1;          // m-group, d-half
  const int q = lane >> 4, c = lane & 15;
  const int chunk = blockIdx.x & 3;
  const int mblk = blockIdx.x >> 2;
  const int row0 = mblk * BM + mg * 32;
  const size_t j0base = (size_t)chunk * JCHUNK;

  // Q fragments resident: A[m=lane&15][k=q*8+j]
  bf16x8 qa[2][8];
  for (int mt = 0; mt < 2; ++mt)
    for (int k = 0; k < 8; ++k)
      qa[mt][k] = *(const bf16x8*)(embn + (size_t)(row0 + mt * 16 + c) * DDIM + k * 32 + q * 8);

  f32x4 oacc[2][8];
  for (int mt = 0; mt < 2; ++mt)
    for (int u = 0; u < 8; ++u) oacc[mt][u] = {0.f, 0.f, 0.f, 0.f};
  float lacc[2][4] = {};

  // prologue: stage first K-tile (32 x 1KB chunks at 1056B pitch, 8 per wave)
  {
    const char* src = (const char*)(embn + j0base * DDIM);
    for (int cc = 0; cc < 8; ++cc) {
      const int ch = w * 8 + cc;
      dma16(src + ch * 1024 + lane * 16, kn + ch * KCHB + lane * 16);
    }
  }

  // kn row r (512B payload) lives at (r>>1)*KCHB + (r&1)*512
  for (int it = 0; it < NITER; ++it) {
    const size_t j0 = j0base + (size_t)it * BN;
    __syncthreads();  // B1: DMA(it) drained; pl reads of iter it-1 drained

    // ---- G1: S[32x64] = Q . Kn^T (kn reads conflict-free via padded pitch) ----
    f32x4 sacc[2][2];
    for (int mt = 0; mt < 2; ++mt)
      for (int nt = 0; nt < 2; ++nt) sacc[mt][nt] = {0.f, 0.f, 0.f, 0.f};
    const int rb0 = (dh * 16 + (c >> 1)) * KCHB + (c & 1) * 512;        // row dh*32+c
    const int rb1 = (dh * 16 + 8 + (c >> 1)) * KCHB + (c & 1) * 512;    // row dh*32+16+c
    for (int k = 0; k < 8; ++k) {
      bf16x8 b0 = *(const bf16x8*)(kn + rb0 + k * 64 + q * 16);
      bf16x8 b1 = *(const bf16x8*)(kn + rb1 + k * 64 + q * 16);
      for (int mt = 0; mt < 2; ++mt) {
        sacc[mt][0] = __builtin_amdgcn_mfma_f32_16x16x32_bf16(qa[mt][k], b0, sacc[mt][0], 0, 0, 0);
        sacc[mt][1] = __builtin_amdgcn_mfma_f32_16x16x32_bf16(qa[mt][k], b1, sacc[mt][1], 0, 0, 0);
      }
    }

    // prefetch V frags into registers NOW: pre-B2 vmcnt(0) finishes them during exp
    bf16x8 vfrag[2][8];
    for (int kk = 0; kk < 2; ++kk)
      for (int u = 0; u < 8; ++u) {
        const int d = dh * 128 + u * 16 + c;
        vfrag[kk][u] = *(const bf16x8*)(vt + (size_t)d * NROWS + j0 + kk * 32 + q * 8);
      }

    // exp (fixed shift 10; cos<=1 so logits<=10, softmax shift-invariant) + P + row sums
    for (int mt = 0; mt < 2; ++mt)
      for (int nt = 0; nt < 2; ++nt)
        for (int r = 0; r < 4; ++r) {
          const float p = __expf(fmaf(SIGMA_INV, sacc[mt][nt][r], -SIGMA_INV));
          lacc[mt][r] += p;
          // C/D layout: row = q*4+r, col = c
          pl[(mg * 32 + mt * 16 + q * 4 + r) * PSTR + dh * 32 + nt * 16 + c] = f2bf(p);
        }

    __syncthreads();  // B2: pl complete, kn reads drained, vfrag loads drained

    // ---- G2: O[32x128] += P[32x64] . V[64x128] ----
    for (int kk = 0; kk < 2; ++kk) {
      bf16x8 ap0 = *(const bf16x8*)(pl + (mg * 32 + c) * PSTR + kk * 32 + q * 8);
      bf16x8 ap1 = *(const bf16x8*)(pl + (mg * 32 + 16 + c) * PSTR + kk * 32 + q * 8);
      for (int u = 0; u < 8; ++u) {
        oacc[0][u] = __builtin_amdgcn_mfma_f32_16x16x32_bf16(ap0, vfrag[kk][u], oacc[0][u], 0, 0, 0);
        oacc[1][u] = __builtin_amdgcn_mfma_f32_16x16x32_bf16(ap1, vfrag[kk][u], oacc[1][u], 0, 0, 0);
      }
    }

    // stage NEXT K-tile: issued after B2 (kn reads all drained), overlaps G2,
    // drained at next B1
    if (it + 1 < NITER) {
      const char* src = (const char*)(embn + (j0base + (size_t)(it + 1) * BN) * DDIM);
      for (int cc = 0; cc < 8; ++cc) {
        const int ch = w * 8 + cc;
        dma16(src + ch * 1024 + lane * 16, kn + ch * KCHB + lane * 16);
      }
    }
  }

  // epilogue: row sums across the 16 c-lanes, then device atomics
  for (int mt = 0; mt < 2; ++mt)
    for (int r = 0; r < 4; ++r) {
      float s = lacc[mt][r];
      s += __shfl_xor(s, 1); s += __shfl_xor(s, 2);
      s += __shfl_xor(s, 4); s += __shfl_xor(s, 8);
      if (c == 0)
        atomicAdd(&l_part[row0 + mt * 16 + q * 4 + r], s);
    }
  for (int mt = 0; mt < 2; ++mt)
    for (int u = 0; u < 8; ++u)
      for (int r = 0; r < 4; ++r)
        atomicAdd(&out[(size_t)(row0 + mt * 16 + q * 4 + r) * DDIM + dh * 128 + u * 16 + c],
                  oacc[mt][u][r]);
}

// ---------------- K4: divide by row sums ----------------
__global__ __launch_bounds__(256) void finalize_k(float* __restrict__ out,
                                                  const float* __restrict__ l_part) {
  const int row = blockIdx.x, t = threadIdx.x;
  out[(size_t)row * DDIM + t] /= l_part[row];
}

extern "C" void kernel_launch(void* const* d_in, const int* in_sizes, int n_in,
                              void* d_out, int out_size, void* d_ws, size_t ws_size,
                              hipStream_t stream) {
  const float* emb = (const float*)d_in[0];
  float* out = (float*)d_out;
  char* ws = (char*)d_ws;
  // ws layout: embn 4MB | vt 4MB | l_part 32KB
  unsigned short* embn = (unsigned short*)ws;
  unsigned short* vt   = (unsigned short*)(ws + ((size_t)4 << 20));
  float* l_part        = (float*)(ws + ((size_t)8 << 20));

  hipMemsetAsync(out, 0, (size_t)NROWS * DDIM * sizeof(float), stream);
  hipMemsetAsync(l_part, 0, (size_t)NROWS * sizeof(float), stream);

  normalize_k<<<NROWS / 4, 256, 0, stream>>>(emb, embn);
  transpose_k<<<dim3(NROWS / 64, DDIM / 64), 256, 0, stream>>>(emb, vt);
  fused_k<<<(NROWS / BM) * NSPLIT, 256, 0, stream>>>(embn, vt, out, l_part);
  finalize_k<<<NROWS, 256, 0, stream>>>(out, l_part);
}